// Round 15
// baseline (632.984 us; speedup 1.0000x reference)
//
#include <hip/hip_runtime.h>
#include <cstdint>
#include <cstddef>

// ---------- types / helpers ----------
using f32x4 = __attribute__((ext_vector_type(4))) float;
using bf16x8 = __attribute__((ext_vector_type(8))) __bf16;
using u16x4 = __attribute__((ext_vector_type(4))) unsigned short;
using u16x8 = __attribute__((ext_vector_type(8))) unsigned short;

#define DEV __device__ __forceinline__

DEV unsigned short f2b(float f) {
  __bf16 h = (__bf16)f;               // native v_cvt (RNE)
  return __builtin_bit_cast(unsigned short, h);
}
DEV float b2f(unsigned short u) {
  uint32_t w = ((uint32_t)u) << 16;
  return __builtin_bit_cast(float, w);
}

// async global->LDS, 16B per lane. LDS dest must be wave-uniform base + lane*16.
DEV void gload16(const unsigned short* g, unsigned short* l) {
  __builtin_amdgcn_global_load_lds(
      (const __attribute__((address_space(1))) void*)g,
      (__attribute__((address_space(3))) void*)l, 16, 0, 0);
}

DEV void waitv(int n) {
  switch (n) {
    case 0: asm volatile("s_waitcnt vmcnt(0)" ::: "memory"); break;
    case 2: asm volatile("s_waitcnt vmcnt(2)" ::: "memory"); break;
    case 8: asm volatile("s_waitcnt vmcnt(8)" ::: "memory"); break;
    default: asm volatile("s_waitcnt vmcnt(0)" ::: "memory"); break;
  }
}

// Problem constants
// B=8, C=256, H=W=128, HEADS=8, hd=32, WS=8, SHIFT=4, nW=256, tokens=131072

// ---------- weight casts + bias/mask table, one launch ----------
__global__ void swin_cvt_all(const float* __restrict__ qkvw, const float* __restrict__ projw,
                             const float* __restrict__ fc1w, const float* __restrict__ fc2w,
                             unsigned short* __restrict__ wq, unsigned short* __restrict__ wp,
                             unsigned short* __restrict__ w1, unsigned short* __restrict__ w2,
                             const float* __restrict__ relb, float* __restrict__ bt) {
  int i = blockIdx.x * 256 + threadIdx.x;           // 0 .. 917503
  if (i < 196608) wq[i] = f2b(qkvw[i]);
  else if (i < 262144) wp[i - 196608] = f2b(projw[i - 196608]);
  else if (i < 524288) w1[i - 262144] = f2b(fc1w[i - 262144]);
  else if (i < 786432) w2[i - 524288] = f2b(fc2w[i - 524288]);
  else {
    int id = i - 786432;                            // 0 .. 131071
    int m = id & 63, n = (id >> 6) & 63, head = (id >> 12) & 7, cls = id >> 15;
    bool eh = cls & 2, ew = cls & 1;
    int nh = n >> 3, nw = n & 7, mh = m >> 3, mw = m & 7;
    int rn = (eh ? ((nh >> 2) + 1) : 0) * 3 + (ew ? ((nw >> 2) + 1) : 0);
    int rm = (eh ? ((mh >> 2) + 1) : 0) * 3 + (ew ? ((mw >> 2) + 1) : 0);
    float v = relb[(size_t)((nh - mh + 7) * 15 + (nw - mw + 7)) * 8 + head];
    if (rn != rm) v -= 100.f;
    bt[id] = v;
  }
}

// ---------- fused LN1: single-pass x read; stats + tile built together ----------
__global__ __launch_bounds__(256)
void swin_ln1win(const float* __restrict__ x,
                 const float* __restrict__ lw, const float* __restrict__ lb,
                 unsigned short* __restrict__ win, unsigned short* __restrict__ xb) {
  __shared__ float sh[512];
  __shared__ float mean_[128], rstd_[128];
  __shared__ unsigned short tile[128 * 260];   // [w][256ch], row stride 520B (2-way free)
  int bh = blockIdx.x; int b = bh >> 7, h = bh & 127;
  int t = threadIdx.x;
  int w = t & 127, ch = t >> 7;
  const float* px = x + (((size_t)(b * 256 + ch * 128)) << 14) + (h << 7) + w;
  float s = 0.f, s2 = 0.f;
  for (int c = 0; c < 128; ++c) {
    float v = px[(size_t)c << 14];
    s += v; s2 += v * v;
    tile[w * 260 + ch * 128 + c] = f2b(v);
  }
  sh[t] = s; sh[256 + t] = s2;
  __syncthreads();
  if (ch == 0) {
    s += sh[t + 128]; s2 += sh[256 + t + 128];
    float mu = s * (1.f / 256.f);
    mean_[w] = mu;
    rstd_[w] = rsqrtf(s2 * (1.f / 256.f) - mu * mu + 1e-5f);
  }
  __syncthreads();
  int hp = (h + 124) & 127;
  int whh = hp >> 3, nh = hp & 7;
  int lg = t & 31, grp = t >> 5;
#pragma unroll
  for (int i = 0; i < 16; ++i) {
    int w2 = (i << 3) + grp;
    float mu = mean_[w2], rs = rstd_[w2];
    int wp_ = (w2 + 124) & 127;
    int wwc = wp_ >> 3, nw = wp_ & 7;
    size_t wt = (size_t)b * 256 + whh * 16 + wwc;
    int n = (nh << 3) + nw;
#pragma unroll
    for (int half = 0; half < 2; ++half) {
      int c = half * 128 + (lg << 2);
      u16x4 raw = *(const u16x4*)&tile[w2 * 260 + c];
      f32x4 lwv = *(const f32x4*)(lw + c);
      f32x4 lbv = *(const f32x4*)(lb + c);
      u16x4 o;
#pragma unroll
      for (int k = 0; k < 4; ++k)
        o[k] = f2b((b2f(raw[k]) - mu) * rs * lwv[k] + lbv[k]);
      *(u16x4*)&win[((wt << 6) + n) * 256 + c] = o;
      *(u16x4*)&xb[(((size_t)bh << 7) + w2) * 256 + c] = raw;
    }
  }
}

// ---------- FUSED QKV + windowed attention (verified r13) ----------
__global__ __launch_bounds__(512)
void swin_qkvattn(const unsigned short* __restrict__ win,
                  const unsigned short* __restrict__ wq,
                  const float* __restrict__ qkvb,
                  const float* __restrict__ btab,
                  unsigned short* __restrict__ attn_out) {
  __shared__ __align__(16) char L[133120];  // 32KB win + 8 x 12544 head regions
  const int wt = blockIdx.x;                // 0..2047
  const int t = threadIdx.x;
  const int lane = t & 63;
  const int head = t >> 6;
  const int cl = lane & 15, g = lane >> 4;

  {
    const unsigned short* src = win + (size_t)wt * 16384;
    int row = t >> 3;
    int sch = (t & 7) ^ (row & 7);
#pragma unroll
    for (int o = 0; o < 4; ++o)
      gload16(src + row * 256 + o * 64 + sch * 8,
              (unsigned short*)(L + o * 8192 + t * 16));
  }
  __syncthreads();

  f32x4 acc1[4][6] = {};
#pragma unroll
  for (int kt = 0; kt < 8; ++kt) {
    bf16x8 af[4], bf[6];
    const char* sub = L + (kt >> 1) * 8192;
    const int kc = (kt & 1) * 4 + g;
#pragma unroll
    for (int i = 0; i < 4; ++i) {
      int tok = i * 16 + cl;
      af[i] = *(const bf16x8*)(sub + tok * 128 + ((kc ^ (tok & 7)) * 16));
    }
#pragma unroll
    for (int j = 0; j < 6; ++j) {
      int col = (j >> 1) * 256 + head * 32 + (j & 1) * 16 + cl;
      bf[j] = *(const bf16x8*)(wq + (size_t)col * 256 + kt * 32 + g * 8);
    }
#pragma unroll
    for (int i = 0; i < 4; ++i)
#pragma unroll
      for (int j = 0; j < 6; ++j)
        acc1[i][j] = __builtin_amdgcn_mfma_f32_16x16x32_bf16(bf[j], af[i], acc1[i][j], 0, 0, 0);
  }

  char* hb = L + 32768 + head * 12544;
#pragma unroll
  for (int i = 0; i < 4; ++i) {
    int tok = i * 16 + cl;
#pragma unroll
    for (int j = 0; j < 6; ++j) {
      int p = j >> 1;
      int c32b = (j & 1) * 16 + (g << 2);
      f32x4 b4 = *(const f32x4*)(qkvb + p * 256 + head * 32 + c32b);
      if (p < 2) {
        u16x4 o;
#pragma unroll
        for (int r = 0; r < 4; ++r) {
          float v = acc1[i][j][r] + b4[r];
          if (p == 0) v *= 0.17677669529663687f;  // 1/sqrt(32)
          o[r] = f2b(v);
        }
        int chunk = ((j & 1) * 2 + (g >> 1)) ^ ((tok >> 1) & 3);
        *(u16x4*)(hb + p * 4096 + tok * 64 + chunk * 16 + (g & 1) * 8) = o;
      } else {
        unsigned short* vt = (unsigned short*)(hb + 8192);
#pragma unroll
        for (int r = 0; r < 4; ++r)
          vt[(c32b + r) * 68 + tok] = f2b(acc1[i][j][r] + b4[r]);
      }
    }
  }
  asm volatile("s_waitcnt lgkmcnt(0)" ::: "memory");
  __builtin_amdgcn_sched_barrier(0);

  bf16x8 qf[4], kf[4];
#pragma unroll
  for (int ni = 0; ni < 4; ++ni) {
    int tok = (ni << 4) + cl;
    int chunk = g ^ ((tok >> 1) & 3);
    qf[ni] = *(const bf16x8*)(hb + tok * 64 + chunk * 16);
    kf[ni] = *(const bf16x8*)(hb + 4096 + tok * 64 + chunk * 16);
  }
  f32x4 s[4][4] = {};
#pragma unroll
  for (int mi = 0; mi < 4; ++mi)
#pragma unroll
    for (int ni = 0; ni < 4; ++ni)
      s[mi][ni] = __builtin_amdgcn_mfma_f32_16x16x32_bf16(kf[mi], qf[ni], s[mi][ni], 0, 0, 0);

  int wi = wt & 255;
  int cls = (((wi >> 4) == 15) ? 2 : 0) + (((wi & 15) == 15) ? 1 : 0);
  const float* bt = btab + (((size_t)(cls << 3) + head) << 12);
#pragma unroll
  for (int ni = 0; ni < 4; ++ni) {
    int n = (ni << 4) + cl;
    float mx = -1e30f;
#pragma unroll
    for (int mi = 0; mi < 4; ++mi) {
      f32x4 bb = *(const f32x4*)&bt[n * 64 + (mi << 4) + (g << 2)];
#pragma unroll
      for (int r = 0; r < 4; ++r) {
        float v = s[mi][ni][r] + bb[r];
        s[mi][ni][r] = v;
        mx = fmaxf(mx, v);
      }
    }
    mx = fmaxf(mx, __shfl_xor(mx, 16));
    mx = fmaxf(mx, __shfl_xor(mx, 32));
    float sum = 0.f;
#pragma unroll
    for (int mi = 0; mi < 4; ++mi)
#pragma unroll
      for (int r = 0; r < 4; ++r) {
        float p = __expf(s[mi][ni][r] - mx);
        s[mi][ni][r] = p;
        sum += p;
      }
    sum += __shfl_xor(sum, 16);
    sum += __shfl_xor(sum, 32);
    float inv = __builtin_amdgcn_rcpf(sum);
#pragma unroll
    for (int mi = 0; mi < 4; ++mi) {
      u16x4 pk;
#pragma unroll
      for (int r = 0; r < 4; ++r) pk[r] = f2b(s[mi][ni][r] * inv);
      int chunk = (mi * 2 + (g >> 1)) ^ (n & 7);
      *(u16x4*)(hb + n * 128 + chunk * 16 + (g & 1) * 8) = pk;
    }
  }
  asm volatile("s_waitcnt lgkmcnt(0)" ::: "memory");
  __builtin_amdgcn_sched_barrier(0);

  union FragU { bf16x8 v; uint64_t q[2]; };
  f32x4 o[4][2] = {};
  const unsigned short* vt = (const unsigned short*)(hb + 8192);
#pragma unroll
  for (int mt = 0; mt < 2; ++mt) {
    FragU vf[2];
#pragma unroll
    for (int dt = 0; dt < 2; ++dt) {
      int d = (dt << 4) + cl;
      const unsigned short* p = vt + d * 68 + (mt << 5) + (g << 3);
      vf[dt].q[0] = *(const uint64_t*)p;
      vf[dt].q[1] = *(const uint64_t*)(p + 4);
    }
#pragma unroll
    for (int ni = 0; ni < 4; ++ni) {
      int n = (ni << 4) + cl;
      int chunk = (mt * 4 + g) ^ (n & 7);
      bf16x8 pa = *(const bf16x8*)(hb + n * 128 + chunk * 16);
#pragma unroll
      for (int dt = 0; dt < 2; ++dt)
        o[ni][dt] = __builtin_amdgcn_mfma_f32_16x16x32_bf16(pa, vf[dt].v, o[ni][dt], 0, 0, 0);
    }
  }

  int b = wt >> 8;
#pragma unroll
  for (int ni = 0; ni < 4; ++ni)
#pragma unroll
    for (int dt = 0; dt < 2; ++dt)
#pragma unroll
      for (int r = 0; r < 4; ++r) {
        int n = (ni << 4) + (g << 2) + r;
        int d = (dt << 4) + cl;
        int hs = ((wi >> 4) << 3) + (n >> 3), ws_ = ((wi & 15) << 3) + (n & 7);
        int hh = (hs + 4) & 127, ww = (ws_ + 4) & 127;
        size_t tok = ((size_t)b << 14) + (hh << 7) + ww;
        attn_out[tok * 256 + (head << 5) + d] = f2b(o[ni][dt][r]);
      }
}

// ---------- proj + residual + FUSED LN2 (verified r13) ----------
__global__ __launch_bounds__(512, 2)
void swin_proj(const unsigned short* __restrict__ A,
               const unsigned short* __restrict__ Wt,
               const float* __restrict__ bias,
               unsigned short* __restrict__ T,
               const unsigned short* __restrict__ xb,
               const float* __restrict__ lw2, const float* __restrict__ lb2,
               unsigned short* __restrict__ tn) {
  constexpr int KT = 4;
  __shared__ __align__(16) unsigned short As[2][16384];
  __shared__ __align__(16) unsigned short Bs[2][16384];
  const int cpx = gridDim.x >> 3;
  const int bid = (blockIdx.x & 7) * cpx + (blockIdx.x >> 3);
  const int m0 = bid << 8;
  const int t = threadIdx.x;
  const int lane = t & 63;
  const int wave = t >> 6;
  const int wr = wave >> 2, wc = wave & 3;
  const int cl = lane & 15, g = lane >> 4;

  const int trow = t >> 3;
  const int ks = (t & 7) ^ (trow & 7);
  const unsigned short* agb = A  + (size_t)(m0 + trow) * 256 + ks * 8;
  const unsigned short* bgb = Wt + (size_t)trow * 256 + ks * 8;

  const int ra = wr * 128 + cl;
  const int rb = wc * 64 + cl;
  const int ka0 = (g ^ (cl & 7)) * 8;

  auto stage = [&](int buf, int kt) {
    const int ko = kt * 64;
#pragma unroll
    for (int l = 0; l < 4; ++l) {
      gload16(agb + (size_t)l * 64 * 256 + ko, &As[buf][l * 4096 + t * 8]);
      gload16(bgb + (size_t)l * 64 * 256 + ko, &Bs[buf][l * 4096 + t * 8]);
    }
  };

  f32x4 acc[8][4] = {};
  bf16x8 afA[8], bfA[4], afB[8], bfB[4];

  auto RD = [&](int buf, int kk, bf16x8* af, bf16x8* bfr) {
    const int ka = ka0 ^ (kk << 5);
#pragma unroll
    for (int i = 0; i < 8; ++i)
      af[i] = *(const bf16x8*)&As[buf][(ra + i * 16) * 64 + ka];
#pragma unroll
    for (int j = 0; j < 4; ++j)
      bfr[j] = *(const bf16x8*)&Bs[buf][(rb + j * 16) * 64 + ka];
  };
  auto MF = [&](bf16x8* af, bf16x8* bfr) {
    __builtin_amdgcn_s_setprio(1);
#pragma unroll
    for (int i = 0; i < 8; ++i)
#pragma unroll
      for (int j = 0; j < 4; ++j)
        acc[i][j] = __builtin_amdgcn_mfma_f32_16x16x32_bf16(bfr[j], af[i], acc[i][j], 0, 0, 0);
    __builtin_amdgcn_s_setprio(0);
  };

  stage(0, 0);
  stage(1, 1);
  waitv(8);
  __builtin_amdgcn_s_barrier();
  RD(0, 0, afA, bfA);
#pragma unroll
  for (int kt = 0; kt < KT; ++kt) {
    const int cur = kt & 1;
    RD(cur, 1, afB, bfB);
    MF(afA, bfA);
    asm volatile("s_waitcnt lgkmcnt(0)" ::: "memory");
    __builtin_amdgcn_sched_barrier(0);
    __builtin_amdgcn_s_barrier();
    if (kt + 2 < KT) stage(cur, kt + 2);
    if (kt + 1 < KT) waitv(8);
    else             waitv(0);
    __builtin_amdgcn_s_barrier();
    if (kt + 1 < KT) RD(cur ^ 1, 0, afA, bfA);
    MF(afB, bfB);
  }

  float s[8], s2v[8];
#pragma unroll
  for (int i = 0; i < 8; ++i) { s[i] = 0.f; s2v[i] = 0.f; }
#pragma unroll
  for (int i = 0; i < 8; ++i) {
    int row = m0 + wr * 128 + i * 16 + cl;
#pragma unroll
    for (int j = 0; j < 4; ++j) {
      int colb = wc * 64 + j * 16 + (g << 2);
      f32x4 b4 = *(const f32x4*)(bias + colb);
      u16x4 xv = *(const u16x4*)(xb + (size_t)row * 256 + colb);
#pragma unroll
      for (int r = 0; r < 4; ++r) {
        float v = acc[i][j][r] + b4[r] + b2f(xv[r]);
        acc[i][j][r] = v;
        s[i] += v; s2v[i] += v * v;
      }
    }
  }
#pragma unroll
  for (int i = 0; i < 8; ++i) {
    s[i]  += __shfl_xor(s[i], 16);  s[i]  += __shfl_xor(s[i], 32);
    s2v[i] += __shfl_xor(s2v[i], 16); s2v[i] += __shfl_xor(s2v[i], 32);
  }
  __syncthreads();
  float* lsum = (float*)&As[0][0];
  if (g == 0) {
#pragma unroll
    for (int i = 0; i < 8; ++i) {
      int rl = wr * 128 + i * 16 + cl;
      lsum[wc * 256 + rl] = s[i];
      lsum[1024 + wc * 256 + rl] = s2v[i];
    }
  }
  __syncthreads();
#pragma unroll
  for (int i = 0; i < 8; ++i) {
    int rl = wr * 128 + i * 16 + cl;
    float ts = lsum[rl] + lsum[256 + rl] + lsum[512 + rl] + lsum[768 + rl];
    float ts2 = lsum[1024 + rl] + lsum[1280 + rl] + lsum[1536 + rl] + lsum[1792 + rl];
    float mu = ts * (1.f / 256.f);
    float rstd = rsqrtf(ts2 * (1.f / 256.f) - mu * mu + 1e-5f);
    int row = m0 + rl;
#pragma unroll
    for (int j = 0; j < 4; ++j) {
      int colb = wc * 64 + j * 16 + (g << 2);
      f32x4 wv = *(const f32x4*)(lw2 + colb);
      f32x4 bv = *(const f32x4*)(lb2 + colb);
      u16x4 oT, on;
#pragma unroll
      for (int r = 0; r < 4; ++r) {
        float v = acc[i][j][r];
        oT[r] = f2b(v);
        on[r] = f2b((v - mu) * rstd * wv[r] + bv[r]);
      }
      *(u16x4*)(T + (size_t)row * 256 + colb) = oT;
      *(u16x4*)(tn + (size_t)row * 256 + colb) = on;
    }
  }
}

// ---------- FUSED FFN: barrier-free GEMM loops, B per-lane from L2 ----------
// At (tn tile) staged once; Hs holds gelu(h2) chunk. A-frags ds_read from the
// proven conflict-free subtiled layout; B-frags per-lane global (w1/w2 are
// 0.5 MB each -> L2-resident on every XCD). Barriers only around the Hs
// handoff (2/q) -> compiler software-pipelines the fully-unrolled kt loops.
__global__ __launch_bounds__(512, 2)
void swin_ffn(const unsigned short* __restrict__ tn,
              const unsigned short* __restrict__ w1,
              const unsigned short* __restrict__ w2,
              const float* __restrict__ b1,
              const float* __restrict__ b2,
              const unsigned short* __restrict__ T,
              float* __restrict__ out) {
  __shared__ __align__(16) unsigned short At[32768];   // 64 KB: 4 subtiles [128][64]
  __shared__ __align__(16) unsigned short Hs[32768];   // 64 KB: 4 subtiles [128][64]
  const int cpx = gridDim.x >> 3;
  const int bid = (blockIdx.x & 7) * cpx + (blockIdx.x >> 3);
  const int m0 = bid << 7;
  const int t = threadIdx.x;
  const int lane = t & 63;
  const int wave = t >> 6;
  const int wr = wave >> 2, wc = wave & 3;
  const int cl = lane & 15, g = lane >> 4;
  const int ra = wr * 64 + cl;              // token row base (+i*16)
  const int rb = wc * 64 + cl;              // out-col base (+j*16), 0..255

  // stage At once: subtile o = k-cols [o*64, o*64+64), [128 rows][64], chunk^=(row&7)
  {
    int row0 = t >> 3;
    int ch = t & 7;
#pragma unroll
    for (int o = 0; o < 4; ++o)
#pragma unroll
      for (int p = 0; p < 2; ++p) {
        int row = p * 64 + row0;
        int sch = ch ^ (row & 7);
        gload16(tn + (size_t)(m0 + row) * 256 + o * 64 + sch * 8,
                &At[o * 8192 + (p * 512 + t) * 8]);
      }
  }
  waitv(0);
  __builtin_amdgcn_s_barrier();

  f32x4 acc2[4][4] = {};
  // per-lane B base pointers (L2-hot weights)
  const unsigned short* w1b = w1 + (size_t)rb * 256;   // + (q*256+j*16)*256 + kt*32 + g*8
  const unsigned short* w2b = w2 + (size_t)rb * 1024;  // + j*16*1024 + q*256 + kt*32 + g*8

  for (int q = 0; q < 4; ++q) {
    f32x4 acc1[4][4] = {};
    // ---- G1: h2[:,q*256+rb..] = tn @ w1^T  (barrier-free, pipelined) ----
#pragma unroll
    for (int kt = 0; kt < 8; ++kt) {
      bf16x8 af[4], bf[4];
#pragma unroll
      for (int i = 0; i < 4; ++i) {
        int row = ra + i * 16;
        int kc = ((kt & 1) * 4 + g) ^ (row & 7);
        af[i] = *(const bf16x8*)&At[(kt >> 1) * 8192 + row * 64 + kc * 8];
      }
#pragma unroll
      for (int j = 0; j < 4; ++j)
        bf[j] = *(const bf16x8*)(w1b + (size_t)(q * 256 + j * 16) * 256 + kt * 32 + g * 8);
#pragma unroll
      for (int i = 0; i < 4; ++i)
#pragma unroll
        for (int j = 0; j < 4; ++j)
          acc1[i][j] = __builtin_amdgcn_mfma_f32_16x16x32_bf16(bf[j], af[i], acc1[i][j], 0, 0, 0);
    }
    // ---- gelu -> Hs (subtile wc, chunk = (j*2+(g>>1)) ^ (row&7)) ----
    __builtin_amdgcn_s_barrier();            // prev q's G2 reads of Hs retired
#pragma unroll
    for (int i = 0; i < 4; ++i) {
      int row = wr * 64 + i * 16 + cl;
#pragma unroll
      for (int j = 0; j < 4; ++j) {
        f32x4 b4 = *(const f32x4*)(b1 + q * 256 + wc * 64 + j * 16 + (g << 2));
        u16x4 o;
#pragma unroll
        for (int r = 0; r < 4; ++r) {
          float v = acc1[i][j][r] + b4[r];
          float p = v * fmaf(v * v, -0.0713548256f, -1.5957691216f);  // -2u
          float e = __expf(p);
          o[r] = f2b(v * __builtin_amdgcn_rcpf(1.f + e));
        }
        int chunk = (j * 2 + (g >> 1)) ^ (row & 7);
        *(u16x4*)((char*)Hs + wc * 16384 + row * 128 + chunk * 16 + (g & 1) * 8) = o;
      }
    }
    asm volatile("s_waitcnt lgkmcnt(0)" ::: "memory");
    __builtin_amdgcn_sched_barrier(0);
    __builtin_amdgcn_s_barrier();            // Hs visible to all waves
    // ---- G2: out += gelu(h2) @ w2^T  (barrier-free, pipelined) ----
#pragma unroll
    for (int kt = 0; kt < 8; ++kt) {
      bf16x8 af2[4], bf2[4];
#pragma unroll
      for (int i = 0; i < 4; ++i) {
        int row = ra + i * 16;
        int kc = ((kt & 1) * 4 + g) ^ (row & 7);
        af2[i] = *(const bf16x8*)&Hs[(kt >> 1) * 8192 + row * 64 + kc * 8];
      }
#pragma unroll
      for (int j = 0; j < 4; ++j)
        bf2[j] = *(const bf16x8*)(w2b + (size_t)(j * 16) * 1024 + q * 256 + kt * 32 + g * 8);
#pragma unroll
      for (int i = 0; i < 4; ++i)
#pragma unroll
        for (int j = 0; j < 4; ++j)
          acc2[i][j] = __builtin_amdgcn_mfma_f32_16x16x32_bf16(bf2[j], af2[i], acc2[i][j], 0, 0, 0);
    }
  }

  // epilogue: bias2 + T residual -> d_out NCHW
#pragma unroll
  for (int i = 0; i < 4; ++i) {
    int row = m0 + wr * 64 + i * 16 + cl;
    int b = row >> 14, hw = row & 16383;
#pragma unroll
    for (int j = 0; j < 4; ++j) {
      int colb = wc * 64 + j * 16 + (g << 2);
      f32x4 b4 = *(const f32x4*)(b2 + colb);
      u16x4 tv = *(const u16x4*)(T + (size_t)row * 256 + colb);
#pragma unroll
      for (int r = 0; r < 4; ++r)
        out[((size_t)(b * 256 + colb + r) << 14) + hw] = acc2[i][j][r] + b4[r] + b2f(tv[r]);
    }
  }
}

// ---------- launch ----------
extern "C" void kernel_launch(void* const* d_in, const int* in_sizes, int n_in,
                              void* d_out, int out_size, void* d_ws, size_t ws_size,
                              hipStream_t stream) {
  const float* x    = (const float*)d_in[0];
  const float* ln1w = (const float*)d_in[1];
  const float* ln1b = (const float*)d_in[2];
  const float* qkvw = (const float*)d_in[3];
  const float* qkvb = (const float*)d_in[4];
  const float* relb = (const float*)d_in[5];
  const float* projw = (const float*)d_in[6];
  const float* projb = (const float*)d_in[7];
  const float* ln2w = (const float*)d_in[8];
  const float* ln2b = (const float*)d_in[9];
  const float* fc1w = (const float*)d_in[10];
  const float* fc1b = (const float*)d_in[11];
  const float* fc2w = (const float*)d_in[12];
  const float* fc2b = (const float*)d_in[13];

  char* ws = (char*)d_ws;
  unsigned short* win      = (unsigned short*)(ws);              // 67,108,864 B
  unsigned short* attn_out = (unsigned short*)(ws + 67108864);   // 67,108,864 B
  unsigned short* tn       = (unsigned short*)(ws + 134217728);  // 67,108,864 B
  unsigned short* T        = (unsigned short*)(ws + 268435456);  // 67,108,864 B
  unsigned short* xb       = (unsigned short*)(ws + 335544320);  // 67,108,864 B
  unsigned short* wq  = (unsigned short*)(ws + 402653184);       // 393,216 B
  unsigned short* wp  = (unsigned short*)(ws + 403046400);       // 131,072 B
  unsigned short* w1  = (unsigned short*)(ws + 403177472);       // 524,288 B
  unsigned short* w2  = (unsigned short*)(ws + 403701760);       // 524,288 B
  float* btab         = (float*)(ws + 404226048);                // 524,288 B -> end 404,750,336

  if (ws_size < 404750336ull) return;

  swin_cvt_all<<<3584, 256, 0, stream>>>(qkvw, projw, fc1w, fc2w, wq, wp, w1, w2, relb, btab);
  swin_ln1win<<<1024, 256, 0, stream>>>(x, ln1w, ln1b, win, xb);
  swin_qkvattn<<<2048, 512, 0, stream>>>(win, wq, qkvb, btab, attn_out);
  swin_proj<<<512, 512, 0, stream>>>(attn_out, wp, projb, T, xb, ln2w, ln2b, tn);
  swin_ffn<<<1024, 512, 0, stream>>>(tn, w1, w2, fc1b, fc2b, T, (float*)d_out);
}

// Round 16
// 511.484 us; speedup vs baseline: 1.2375x; 1.2375x over previous
//
#include <hip/hip_runtime.h>
#include <cstdint>
#include <cstddef>

// ---------- types / helpers ----------
using f32x4 = __attribute__((ext_vector_type(4))) float;
using bf16x8 = __attribute__((ext_vector_type(8))) __bf16;
using u16x4 = __attribute__((ext_vector_type(4))) unsigned short;
using u16x8 = __attribute__((ext_vector_type(8))) unsigned short;

#define DEV __device__ __forceinline__

DEV unsigned short f2b(float f) {
  __bf16 h = (__bf16)f;               // native v_cvt (RNE)
  return __builtin_bit_cast(unsigned short, h);
}
DEV float b2f(unsigned short u) {
  uint32_t w = ((uint32_t)u) << 16;
  return __builtin_bit_cast(float, w);
}

// async global->LDS, 16B per lane. LDS dest must be wave-uniform base + lane*16.
DEV void gload16(const unsigned short* g, unsigned short* l) {
  __builtin_amdgcn_global_load_lds(
      (const __attribute__((address_space(1))) void*)g,
      (__attribute__((address_space(3))) void*)l, 16, 0, 0);
}

DEV void waitv(int n) {
  switch (n) {
    case 0: asm volatile("s_waitcnt vmcnt(0)" ::: "memory"); break;
    case 2: asm volatile("s_waitcnt vmcnt(2)" ::: "memory"); break;
    case 4: asm volatile("s_waitcnt vmcnt(4)" ::: "memory"); break;
    case 8: asm volatile("s_waitcnt vmcnt(8)" ::: "memory"); break;
    default: asm volatile("s_waitcnt vmcnt(0)" ::: "memory"); break;
  }
}

// Problem constants
// B=8, C=256, H=W=128, HEADS=8, hd=32, WS=8, SHIFT=4, nW=256, tokens=131072

// ---------- weight casts + bias/mask table, one launch ----------
__global__ void swin_cvt_all(const float* __restrict__ qkvw, const float* __restrict__ projw,
                             const float* __restrict__ fc1w, const float* __restrict__ fc2w,
                             unsigned short* __restrict__ wq, unsigned short* __restrict__ wp,
                             unsigned short* __restrict__ w1, unsigned short* __restrict__ w2,
                             const float* __restrict__ relb, float* __restrict__ bt) {
  int i = blockIdx.x * 256 + threadIdx.x;           // 0 .. 917503
  if (i < 196608) wq[i] = f2b(qkvw[i]);
  else if (i < 262144) wp[i - 196608] = f2b(projw[i - 196608]);
  else if (i < 524288) w1[i - 262144] = f2b(fc1w[i - 262144]);
  else if (i < 786432) w2[i - 524288] = f2b(fc2w[i - 524288]);
  else {
    int id = i - 786432;                            // 0 .. 131071
    int m = id & 63, n = (id >> 6) & 63, head = (id >> 12) & 7, cls = id >> 15;
    bool eh = cls & 2, ew = cls & 1;
    int nh = n >> 3, nw = n & 7, mh = m >> 3, mw = m & 7;
    int rn = (eh ? ((nh >> 2) + 1) : 0) * 3 + (ew ? ((nw >> 2) + 1) : 0);
    int rm = (eh ? ((mh >> 2) + 1) : 0) * 3 + (ew ? ((mw >> 2) + 1) : 0);
    float v = relb[(size_t)((nh - mh + 7) * 15 + (nw - mw + 7)) * 8 + head];
    if (rn != rm) v -= 100.f;
    bt[id] = v;
  }
}

// ---------- fused LN1: single-pass x read; stats + tile built together ----------
__global__ __launch_bounds__(256)
void swin_ln1win(const float* __restrict__ x,
                 const float* __restrict__ lw, const float* __restrict__ lb,
                 unsigned short* __restrict__ win, unsigned short* __restrict__ xb) {
  __shared__ float sh[512];
  __shared__ float mean_[128], rstd_[128];
  __shared__ unsigned short tile[128 * 260];   // [w][256ch], row stride 520B (2-way free)
  int bh = blockIdx.x; int b = bh >> 7, h = bh & 127;
  int t = threadIdx.x;
  int w = t & 127, ch = t >> 7;
  const float* px = x + (((size_t)(b * 256 + ch * 128)) << 14) + (h << 7) + w;
  float s = 0.f, s2 = 0.f;
  for (int c = 0; c < 128; ++c) {
    float v = px[(size_t)c << 14];
    s += v; s2 += v * v;
    tile[w * 260 + ch * 128 + c] = f2b(v);
  }
  sh[t] = s; sh[256 + t] = s2;
  __syncthreads();
  if (ch == 0) {
    s += sh[t + 128]; s2 += sh[256 + t + 128];
    float mu = s * (1.f / 256.f);
    mean_[w] = mu;
    rstd_[w] = rsqrtf(s2 * (1.f / 256.f) - mu * mu + 1e-5f);
  }
  __syncthreads();
  int hp = (h + 124) & 127;
  int whh = hp >> 3, nh = hp & 7;
  int lg = t & 31, grp = t >> 5;
#pragma unroll
  for (int i = 0; i < 16; ++i) {
    int w2 = (i << 3) + grp;
    float mu = mean_[w2], rs = rstd_[w2];
    int wp_ = (w2 + 124) & 127;
    int wwc = wp_ >> 3, nw = wp_ & 7;
    size_t wt = (size_t)b * 256 + whh * 16 + wwc;
    int n = (nh << 3) + nw;
#pragma unroll
    for (int half = 0; half < 2; ++half) {
      int c = half * 128 + (lg << 2);
      u16x4 raw = *(const u16x4*)&tile[w2 * 260 + c];
      f32x4 lwv = *(const f32x4*)(lw + c);
      f32x4 lbv = *(const f32x4*)(lb + c);
      u16x4 o;
#pragma unroll
      for (int k = 0; k < 4; ++k)
        o[k] = f2b((b2f(raw[k]) - mu) * rs * lwv[k] + lbv[k]);
      *(u16x4*)&win[((wt << 6) + n) * 256 + c] = o;
      *(u16x4*)&xb[(((size_t)bh << 7) + w2) * 256 + c] = raw;
    }
  }
}

// ---------- FUSED QKV + windowed attention (verified r13) ----------
__global__ __launch_bounds__(512)
void swin_qkvattn(const unsigned short* __restrict__ win,
                  const unsigned short* __restrict__ wq,
                  const float* __restrict__ qkvb,
                  const float* __restrict__ btab,
                  unsigned short* __restrict__ attn_out) {
  __shared__ __align__(16) char L[133120];  // 32KB win + 8 x 12544 head regions
  const int wt = blockIdx.x;                // 0..2047
  const int t = threadIdx.x;
  const int lane = t & 63;
  const int head = t >> 6;
  const int cl = lane & 15, g = lane >> 4;

  {
    const unsigned short* src = win + (size_t)wt * 16384;
    int row = t >> 3;
    int sch = (t & 7) ^ (row & 7);
#pragma unroll
    for (int o = 0; o < 4; ++o)
      gload16(src + row * 256 + o * 64 + sch * 8,
              (unsigned short*)(L + o * 8192 + t * 16));
  }
  __syncthreads();

  f32x4 acc1[4][6] = {};
#pragma unroll
  for (int kt = 0; kt < 8; ++kt) {
    bf16x8 af[4], bf[6];
    const char* sub = L + (kt >> 1) * 8192;
    const int kc = (kt & 1) * 4 + g;
#pragma unroll
    for (int i = 0; i < 4; ++i) {
      int tok = i * 16 + cl;
      af[i] = *(const bf16x8*)(sub + tok * 128 + ((kc ^ (tok & 7)) * 16));
    }
#pragma unroll
    for (int j = 0; j < 6; ++j) {
      int col = (j >> 1) * 256 + head * 32 + (j & 1) * 16 + cl;
      bf[j] = *(const bf16x8*)(wq + (size_t)col * 256 + kt * 32 + g * 8);
    }
#pragma unroll
    for (int i = 0; i < 4; ++i)
#pragma unroll
      for (int j = 0; j < 6; ++j)
        acc1[i][j] = __builtin_amdgcn_mfma_f32_16x16x32_bf16(bf[j], af[i], acc1[i][j], 0, 0, 0);
  }

  char* hb = L + 32768 + head * 12544;
#pragma unroll
  for (int i = 0; i < 4; ++i) {
    int tok = i * 16 + cl;
#pragma unroll
    for (int j = 0; j < 6; ++j) {
      int p = j >> 1;
      int c32b = (j & 1) * 16 + (g << 2);
      f32x4 b4 = *(const f32x4*)(qkvb + p * 256 + head * 32 + c32b);
      if (p < 2) {
        u16x4 o;
#pragma unroll
        for (int r = 0; r < 4; ++r) {
          float v = acc1[i][j][r] + b4[r];
          if (p == 0) v *= 0.17677669529663687f;  // 1/sqrt(32)
          o[r] = f2b(v);
        }
        int chunk = ((j & 1) * 2 + (g >> 1)) ^ ((tok >> 1) & 3);
        *(u16x4*)(hb + p * 4096 + tok * 64 + chunk * 16 + (g & 1) * 8) = o;
      } else {
        unsigned short* vt = (unsigned short*)(hb + 8192);
#pragma unroll
        for (int r = 0; r < 4; ++r)
          vt[(c32b + r) * 68 + tok] = f2b(acc1[i][j][r] + b4[r]);
      }
    }
  }
  asm volatile("s_waitcnt lgkmcnt(0)" ::: "memory");
  __builtin_amdgcn_sched_barrier(0);

  bf16x8 qf[4], kf[4];
#pragma unroll
  for (int ni = 0; ni < 4; ++ni) {
    int tok = (ni << 4) + cl;
    int chunk = g ^ ((tok >> 1) & 3);
    qf[ni] = *(const bf16x8*)(hb + tok * 64 + chunk * 16);
    kf[ni] = *(const bf16x8*)(hb + 4096 + tok * 64 + chunk * 16);
  }
  f32x4 s[4][4] = {};
#pragma unroll
  for (int mi = 0; mi < 4; ++mi)
#pragma unroll
    for (int ni = 0; ni < 4; ++ni)
      s[mi][ni] = __builtin_amdgcn_mfma_f32_16x16x32_bf16(kf[mi], qf[ni], s[mi][ni], 0, 0, 0);

  int wi = wt & 255;
  int cls = (((wi >> 4) == 15) ? 2 : 0) + (((wi & 15) == 15) ? 1 : 0);
  const float* bt = btab + (((size_t)(cls << 3) + head) << 12);
#pragma unroll
  for (int ni = 0; ni < 4; ++ni) {
    int n = (ni << 4) + cl;
    float mx = -1e30f;
#pragma unroll
    for (int mi = 0; mi < 4; ++mi) {
      f32x4 bb = *(const f32x4*)&bt[n * 64 + (mi << 4) + (g << 2)];
#pragma unroll
      for (int r = 0; r < 4; ++r) {
        float v = s[mi][ni][r] + bb[r];
        s[mi][ni][r] = v;
        mx = fmaxf(mx, v);
      }
    }
    mx = fmaxf(mx, __shfl_xor(mx, 16));
    mx = fmaxf(mx, __shfl_xor(mx, 32));
    float sum = 0.f;
#pragma unroll
    for (int mi = 0; mi < 4; ++mi)
#pragma unroll
      for (int r = 0; r < 4; ++r) {
        float p = __expf(s[mi][ni][r] - mx);
        s[mi][ni][r] = p;
        sum += p;
      }
    sum += __shfl_xor(sum, 16);
    sum += __shfl_xor(sum, 32);
    float inv = __builtin_amdgcn_rcpf(sum);
#pragma unroll
    for (int mi = 0; mi < 4; ++mi) {
      u16x4 pk;
#pragma unroll
      for (int r = 0; r < 4; ++r) pk[r] = f2b(s[mi][ni][r] * inv);
      int chunk = (mi * 2 + (g >> 1)) ^ (n & 7);
      *(u16x4*)(hb + n * 128 + chunk * 16 + (g & 1) * 8) = pk;
    }
  }
  asm volatile("s_waitcnt lgkmcnt(0)" ::: "memory");
  __builtin_amdgcn_sched_barrier(0);

  union FragU { bf16x8 v; uint64_t q[2]; };
  f32x4 o[4][2] = {};
  const unsigned short* vt = (const unsigned short*)(hb + 8192);
#pragma unroll
  for (int mt = 0; mt < 2; ++mt) {
    FragU vf[2];
#pragma unroll
    for (int dt = 0; dt < 2; ++dt) {
      int d = (dt << 4) + cl;
      const unsigned short* p = vt + d * 68 + (mt << 5) + (g << 3);
      vf[dt].q[0] = *(const uint64_t*)p;
      vf[dt].q[1] = *(const uint64_t*)(p + 4);
    }
#pragma unroll
    for (int ni = 0; ni < 4; ++ni) {
      int n = (ni << 4) + cl;
      int chunk = (mt * 4 + g) ^ (n & 7);
      bf16x8 pa = *(const bf16x8*)(hb + n * 128 + chunk * 16);
#pragma unroll
      for (int dt = 0; dt < 2; ++dt)
        o[ni][dt] = __builtin_amdgcn_mfma_f32_16x16x32_bf16(pa, vf[dt].v, o[ni][dt], 0, 0, 0);
    }
  }

  int b = wt >> 8;
#pragma unroll
  for (int ni = 0; ni < 4; ++ni)
#pragma unroll
    for (int dt = 0; dt < 2; ++dt)
#pragma unroll
      for (int r = 0; r < 4; ++r) {
        int n = (ni << 4) + (g << 2) + r;
        int d = (dt << 4) + cl;
        int hs = ((wi >> 4) << 3) + (n >> 3), ws_ = ((wi & 15) << 3) + (n & 7);
        int hh = (hs + 4) & 127, ww = (ws_ + 4) & 127;
        size_t tok = ((size_t)b << 14) + (hh << 7) + ww;
        attn_out[tok * 256 + (head << 5) + d] = f2b(o[ni][dt][r]);
      }
}

// ---------- proj + residual + FUSED LN2 (verified r13) ----------
__global__ __launch_bounds__(512, 2)
void swin_proj(const unsigned short* __restrict__ A,
               const unsigned short* __restrict__ Wt,
               const float* __restrict__ bias,
               unsigned short* __restrict__ T,
               const unsigned short* __restrict__ xb,
               const float* __restrict__ lw2, const float* __restrict__ lb2,
               unsigned short* __restrict__ tn) {
  constexpr int KT = 4;
  __shared__ __align__(16) unsigned short As[2][16384];
  __shared__ __align__(16) unsigned short Bs[2][16384];
  const int cpx = gridDim.x >> 3;
  const int bid = (blockIdx.x & 7) * cpx + (blockIdx.x >> 3);
  const int m0 = bid << 8;
  const int t = threadIdx.x;
  const int lane = t & 63;
  const int wave = t >> 6;
  const int wr = wave >> 2, wc = wave & 3;
  const int cl = lane & 15, g = lane >> 4;

  const int trow = t >> 3;
  const int ks = (t & 7) ^ (trow & 7);
  const unsigned short* agb = A  + (size_t)(m0 + trow) * 256 + ks * 8;
  const unsigned short* bgb = Wt + (size_t)trow * 256 + ks * 8;

  const int ra = wr * 128 + cl;
  const int rb = wc * 64 + cl;
  const int ka0 = (g ^ (cl & 7)) * 8;

  auto stage = [&](int buf, int kt) {
    const int ko = kt * 64;
#pragma unroll
    for (int l = 0; l < 4; ++l) {
      gload16(agb + (size_t)l * 64 * 256 + ko, &As[buf][l * 4096 + t * 8]);
      gload16(bgb + (size_t)l * 64 * 256 + ko, &Bs[buf][l * 4096 + t * 8]);
    }
  };

  f32x4 acc[8][4] = {};
  bf16x8 afA[8], bfA[4], afB[8], bfB[4];

  auto RD = [&](int buf, int kk, bf16x8* af, bf16x8* bfr) {
    const int ka = ka0 ^ (kk << 5);
#pragma unroll
    for (int i = 0; i < 8; ++i)
      af[i] = *(const bf16x8*)&As[buf][(ra + i * 16) * 64 + ka];
#pragma unroll
    for (int j = 0; j < 4; ++j)
      bfr[j] = *(const bf16x8*)&Bs[buf][(rb + j * 16) * 64 + ka];
  };
  auto MF = [&](bf16x8* af, bf16x8* bfr) {
    __builtin_amdgcn_s_setprio(1);
#pragma unroll
    for (int i = 0; i < 8; ++i)
#pragma unroll
      for (int j = 0; j < 4; ++j)
        acc[i][j] = __builtin_amdgcn_mfma_f32_16x16x32_bf16(bfr[j], af[i], acc[i][j], 0, 0, 0);
    __builtin_amdgcn_s_setprio(0);
  };

  stage(0, 0);
  stage(1, 1);
  waitv(8);
  __builtin_amdgcn_s_barrier();
  RD(0, 0, afA, bfA);
#pragma unroll
  for (int kt = 0; kt < KT; ++kt) {
    const int cur = kt & 1;
    RD(cur, 1, afB, bfB);
    MF(afA, bfA);
    asm volatile("s_waitcnt lgkmcnt(0)" ::: "memory");
    __builtin_amdgcn_sched_barrier(0);
    __builtin_amdgcn_s_barrier();
    if (kt + 2 < KT) stage(cur, kt + 2);
    if (kt + 1 < KT) waitv(8);
    else             waitv(0);
    __builtin_amdgcn_s_barrier();
    if (kt + 1 < KT) RD(cur ^ 1, 0, afA, bfA);
    MF(afB, bfB);
  }

  float s[8], s2v[8];
#pragma unroll
  for (int i = 0; i < 8; ++i) { s[i] = 0.f; s2v[i] = 0.f; }
#pragma unroll
  for (int i = 0; i < 8; ++i) {
    int row = m0 + wr * 128 + i * 16 + cl;
#pragma unroll
    for (int j = 0; j < 4; ++j) {
      int colb = wc * 64 + j * 16 + (g << 2);
      f32x4 b4 = *(const f32x4*)(bias + colb);
      u16x4 xv = *(const u16x4*)(xb + (size_t)row * 256 + colb);
#pragma unroll
      for (int r = 0; r < 4; ++r) {
        float v = acc[i][j][r] + b4[r] + b2f(xv[r]);
        acc[i][j][r] = v;
        s[i] += v; s2v[i] += v * v;
      }
    }
  }
#pragma unroll
  for (int i = 0; i < 8; ++i) {
    s[i]  += __shfl_xor(s[i], 16);  s[i]  += __shfl_xor(s[i], 32);
    s2v[i] += __shfl_xor(s2v[i], 16); s2v[i] += __shfl_xor(s2v[i], 32);
  }
  __syncthreads();
  float* lsum = (float*)&As[0][0];
  if (g == 0) {
#pragma unroll
    for (int i = 0; i < 8; ++i) {
      int rl = wr * 128 + i * 16 + cl;
      lsum[wc * 256 + rl] = s[i];
      lsum[1024 + wc * 256 + rl] = s2v[i];
    }
  }
  __syncthreads();
#pragma unroll
  for (int i = 0; i < 8; ++i) {
    int rl = wr * 128 + i * 16 + cl;
    float ts = lsum[rl] + lsum[256 + rl] + lsum[512 + rl] + lsum[768 + rl];
    float ts2 = lsum[1024 + rl] + lsum[1280 + rl] + lsum[1536 + rl] + lsum[1792 + rl];
    float mu = ts * (1.f / 256.f);
    float rstd = rsqrtf(ts2 * (1.f / 256.f) - mu * mu + 1e-5f);
    int row = m0 + rl;
#pragma unroll
    for (int j = 0; j < 4; ++j) {
      int colb = wc * 64 + j * 16 + (g << 2);
      f32x4 wv = *(const f32x4*)(lw2 + colb);
      f32x4 bv = *(const f32x4*)(lb2 + colb);
      u16x4 oT, on;
#pragma unroll
      for (int r = 0; r < 4; ++r) {
        float v = acc[i][j][r];
        oT[r] = f2b(v);
        on[r] = f2b((v - mu) * rstd * wv[r] + bv[r]);
      }
      *(u16x4*)(T + (size_t)row * 256 + colb) = oT;
      *(u16x4*)(tn + (size_t)row * 256 + colb) = on;
    }
  }
}

// ---------- FUSED FFN (r14 staged-B structure + A-prefetch w/ counted lgkm) ----------
// At = tn tile staged ONCE; Hs = gelu(h2) chunk; Bs = [256][32] dbuf (w1/w2).
// A-frags (persistent tiles) are ping-pong prefetched: af(kt+1) issued AFTER
// the Bs reads, waited with lgkmcnt(4) (in-order DS retire -> Bs done, af in
// flight under MFMA). Removes one ds_read chain per phase vs r14.
__global__ __launch_bounds__(512)
void swin_ffn(const unsigned short* __restrict__ tn,
              const unsigned short* __restrict__ w1,
              const unsigned short* __restrict__ w2,
              const float* __restrict__ b1,
              const float* __restrict__ b2,
              const unsigned short* __restrict__ T,
              float* __restrict__ out) {
  __shared__ __align__(16) unsigned short At[32768];   // 64 KB
  __shared__ __align__(16) unsigned short Hs[32768];   // 64 KB
  __shared__ __align__(16) unsigned short Bs[2][8192]; // 32 KB
  const int cpx = gridDim.x >> 3;
  const int bid = (blockIdx.x & 7) * cpx + (blockIdx.x >> 3);
  const int m0 = bid << 7;
  const int t = threadIdx.x;
  const int lane = t & 63;
  const int wave = t >> 6;
  const int wr = wave >> 2, wc = wave & 3;
  const int cl = lane & 15, g = lane >> 4;

  const int arow = t >> 2;                  // 0..127 (B staging)
  const int ks = (t & 3) ^ ((arow >> 1) & 3);
  const int ka = (g ^ ((cl >> 1) & 3)) * 8;
  const int ra = wr * 64 + cl;
  const int rb = wc * 64 + cl;

  auto stageB1 = [&](int buf, int q, int kt) {
    const unsigned short* wg = w1 + (size_t)(q * 256 + arow) * 256 + kt * 32 + ks * 8;
    gload16(wg, &Bs[buf][t * 8]);
    gload16(wg + 32768, &Bs[buf][4096 + t * 8]);
  };
  auto stageB2 = [&](int buf, int q, int kt) {
    const unsigned short* wg = w2 + (size_t)arow * 1024 + q * 256 + kt * 32 + ks * 8;
    gload16(wg, &Bs[buf][t * 8]);
    gload16(wg + 131072, &Bs[buf][4096 + t * 8]);
  };

  // stage At once: subtile o = k-cols [o*64, o*64+64), [128 rows][64], chunk^=(row&7)
  {
    int row0 = t >> 3;
    int ch = t & 7;
#pragma unroll
    for (int o = 0; o < 4; ++o)
#pragma unroll
      for (int p = 0; p < 2; ++p) {
        int row = p * 64 + row0;
        int sch = ch ^ (row & 7);
        gload16(tn + (size_t)(m0 + row) * 256 + o * 64 + sch * 8,
                &At[o * 8192 + (p * 512 + t) * 8]);
      }
  }

  // A-frag readers from persistent tiles (no sync needed once resident)
  auto RDA = [&](const unsigned short* tile, int kt, bf16x8* af) {
#pragma unroll
    for (int i = 0; i < 4; ++i) {
      int row = ra + i * 16;
      int kc = ((kt & 1) * 4 + g) ^ (row & 7);
      af[i] = *(const bf16x8*)&tile[(kt >> 1) * 8192 + row * 64 + kc * 8];
    }
  };

  f32x4 acc2[4][4] = {};

  for (int q = 0; q < 4; ++q) {
    f32x4 acc1[4][4] = {};
    stageB1(0, q, 0); stageB1(1, q, 1);
    bf16x8 afp[2][4];
    if (q == 0) {
      waitv(4);                            // At resident (B1(0),B1(1) still out)
      __builtin_amdgcn_s_barrier();        // all waves' At portions landed
    }
    RDA(At, 0, afp[0]);                    // prologue A-frags for kt=0
#pragma unroll
    for (int kt = 0; kt < 8; ++kt) {
      const int cur = kt & 1;
      waitv(kt < 7 ? 2 : 0);               // Bs[cur] arrived (this wave)
      __builtin_amdgcn_s_barrier();        // all waves
      bf16x8 bf[4];
#pragma unroll
      for (int j = 0; j < 4; ++j)
        bf[j] = *(const bf16x8*)&Bs[cur][(rb + j * 16) * 32 + ka];
      __builtin_amdgcn_sched_barrier(0);   // pin: bf reads issue before af(kt+1)
      if (kt < 7) RDA(At, kt + 1, afp[(kt + 1) & 1]);
      if (kt < 7) asm volatile("s_waitcnt lgkmcnt(4)" ::: "memory");  // bf done
      else        asm volatile("s_waitcnt lgkmcnt(0)" ::: "memory");
      __builtin_amdgcn_sched_barrier(0);
      __builtin_amdgcn_s_barrier();        // all waves done reading Bs[cur]
      if (kt + 2 < 8) stageB1(cur, q, kt + 2);
      __builtin_amdgcn_s_setprio(1);
#pragma unroll
      for (int i = 0; i < 4; ++i)
#pragma unroll
        for (int j = 0; j < 4; ++j)
          acc1[i][j] = __builtin_amdgcn_mfma_f32_16x16x32_bf16(bf[j], afp[kt & 1][i],
                                                               acc1[i][j], 0, 0, 0);
      __builtin_amdgcn_s_setprio(0);
    }
    stageB2(0, q, 0); stageB2(1, q, 1);        // prefetch w2 under gelu
    // gelu -> Hs subtile wc: [128][64], chunk = (j*2+(g>>1)) ^ (row&7)
#pragma unroll
    for (int i = 0; i < 4; ++i) {
      int row = wr * 64 + i * 16 + cl;
#pragma unroll
      for (int j = 0; j < 4; ++j) {
        f32x4 b4 = *(const f32x4*)(b1 + q * 256 + wc * 64 + j * 16 + (g << 2));
        u16x4 o;
#pragma unroll
        for (int r = 0; r < 4; ++r) {
          float v = acc1[i][j][r] + b4[r];
          float p = v * fmaf(v * v, -0.0713548256f, -1.5957691216f);  // -2u
          float e = __expf(p);
          o[r] = f2b(v * __builtin_amdgcn_rcpf(1.f + e));
        }
        int chunk = (j * 2 + (g >> 1)) ^ (row & 7);
        *(u16x4*)((char*)Hs + wc * 16384 + row * 128 + chunk * 16 + (g & 1) * 8) = o;
      }
    }
    asm volatile("s_waitcnt lgkmcnt(0)" ::: "memory");
    __builtin_amdgcn_sched_barrier(0);
    __builtin_amdgcn_s_barrier();            // Hs visible to all waves
    bf16x8 afp2[2][4];
    RDA(Hs, 0, afp2[0]);                     // prologue A-frags for G2 kt=0
#pragma unroll
    for (int kt = 0; kt < 8; ++kt) {         // G2: BK=32 over this q's 256 h
      const int cur = kt & 1;
      waitv(kt < 7 ? 2 : 0);
      __builtin_amdgcn_s_barrier();
      bf16x8 bf2[4];
#pragma unroll
      for (int j = 0; j < 4; ++j)
        bf2[j] = *(const bf16x8*)&Bs[cur][(rb + j * 16) * 32 + ka];
      __builtin_amdgcn_sched_barrier(0);
      if (kt < 7) RDA(Hs, kt + 1, afp2[(kt + 1) & 1]);
      if (kt < 7) asm volatile("s_waitcnt lgkmcnt(4)" ::: "memory");
      else        asm volatile("s_waitcnt lgkmcnt(0)" ::: "memory");
      __builtin_amdgcn_sched_barrier(0);
      __builtin_amdgcn_s_barrier();
      if (kt + 2 < 8) stageB2(cur, q, kt + 2);
      __builtin_amdgcn_s_setprio(1);
#pragma unroll
      for (int i = 0; i < 4; ++i)
#pragma unroll
        for (int j = 0; j < 4; ++j)
          acc2[i][j] = __builtin_amdgcn_mfma_f32_16x16x32_bf16(bf2[j], afp2[kt & 1][i],
                                                               acc2[i][j], 0, 0, 0);
      __builtin_amdgcn_s_setprio(0);
    }
  }

  // epilogue: bias2 + T residual -> d_out NCHW
#pragma unroll
  for (int i = 0; i < 4; ++i) {
    int row = m0 + wr * 64 + i * 16 + cl;
    int b = row >> 14, hw = row & 16383;
#pragma unroll
    for (int j = 0; j < 4; ++j) {
      int colb = wc * 64 + j * 16 + (g << 2);
      f32x4 b4 = *(const f32x4*)(b2 + colb);
      u16x4 tv = *(const u16x4*)(T + (size_t)row * 256 + colb);
#pragma unroll
      for (int r = 0; r < 4; ++r)
        out[((size_t)(b * 256 + colb + r) << 14) + hw] = acc2[i][j][r] + b4[r] + b2f(tv[r]);
    }
  }
}

// ---------- launch ----------
extern "C" void kernel_launch(void* const* d_in, const int* in_sizes, int n_in,
                              void* d_out, int out_size, void* d_ws, size_t ws_size,
                              hipStream_t stream) {
  const float* x    = (const float*)d_in[0];
  const float* ln1w = (const float*)d_in[1];
  const float* ln1b = (const float*)d_in[2];
  const float* qkvw = (const float*)d_in[3];
  const float* qkvb = (const float*)d_in[4];
  const float* relb = (const float*)d_in[5];
  const float* projw = (const float*)d_in[6];
  const float* projb = (const float*)d_in[7];
  const float* ln2w = (const float*)d_in[8];
  const float* ln2b = (const float*)d_in[9];
  const float* fc1w = (const float*)d_in[10];
  const float* fc1b = (const float*)d_in[11];
  const float* fc2w = (const float*)d_in[12];
  const float* fc2b = (const float*)d_in[13];

  char* ws = (char*)d_ws;
  unsigned short* win      = (unsigned short*)(ws);              // 67,108,864 B
  unsigned short* attn_out = (unsigned short*)(ws + 67108864);   // 67,108,864 B
  unsigned short* tn       = (unsigned short*)(ws + 134217728);  // 67,108,864 B
  unsigned short* T        = (unsigned short*)(ws + 268435456);  // 67,108,864 B
  unsigned short* xb       = (unsigned short*)(ws + 335544320);  // 67,108,864 B
  unsigned short* wq  = (unsigned short*)(ws + 402653184);       // 393,216 B
  unsigned short* wp  = (unsigned short*)(ws + 403046400);       // 131,072 B
  unsigned short* w1  = (unsigned short*)(ws + 403177472);       // 524,288 B
  unsigned short* w2  = (unsigned short*)(ws + 403701760);       // 524,288 B
  float* btab         = (float*)(ws + 404226048);                // 524,288 B -> end 404,750,336

  if (ws_size < 404750336ull) return;

  swin_cvt_all<<<3584, 256, 0, stream>>>(qkvw, projw, fc1w, fc2w, wq, wp, w1, w2, relb, btab);
  swin_ln1win<<<1024, 256, 0, stream>>>(x, ln1w, ln1b, win, xb);
  swin_qkvattn<<<2048, 512, 0, stream>>>(win, wq, qkvb, btab, attn_out);
  swin_proj<<<512, 512, 0, stream>>>(attn_out, wp, projb, T, xb, ln2w, ln2b, tn);
  swin_ffn<<<1024, 512, 0, stream>>>(tn, w1, w2, fc1b, fc2b, T, (float*)d_out);
}